// Round 1
// baseline (1576.102 us; speedup 1.0000x reference)
//
#include <hip/hip_runtime.h>
#include <math.h>

#define FIN  1433
#define HID  16
#define NCLS 7

// K1: fused dual projection over x.  One thread per node row.
// acc_rel[c] = sum_k x[row,k]*w_rel1[k,c];  agg_init[c] = b1[c] + sum_k x[row,k]*w_root1[k,c]
// Weight loads are wave-uniform (k uniform) -> scalar loads (SGPR), x load is 1 dword/iter.
__global__ __launch_bounds__(256) void k1_proj(
    const float* __restrict__ x,
    const float* __restrict__ w_root, const float* __restrict__ w_rel,
    const float* __restrict__ b_rel,
    float* __restrict__ p_rel, float* __restrict__ agg, int n) {
  int row = blockIdx.x * 256 + threadIdx.x;
  if (row >= n) return;
  const float* xr = x + (size_t)row * FIN;
  float ar[HID], ao[HID];
#pragma unroll
  for (int c = 0; c < HID; ++c) { ar[c] = 0.f; ao[c] = 0.f; }
  for (int k = 0; k < FIN; ++k) {
    float xv = xr[k];
    const float* __restrict__ wr = w_rel + k * HID;
    const float* __restrict__ wo = w_root + k * HID;
#pragma unroll
    for (int c = 0; c < HID; ++c) {
      ar[c] = fmaf(xv, wr[c], ar[c]);
      ao[c] = fmaf(xv, wo[c], ao[c]);
    }
  }
  // row*HID*4 = row*64 bytes -> 16B aligned, vectorize stores
  float4* pr4 = (float4*)(p_rel + (size_t)row * HID);
  float4* ag4 = (float4*)(agg  + (size_t)row * HID);
#pragma unroll
  for (int q = 0; q < 4; ++q) {
    float4 a, b;
    a.x = ar[4*q+0]; a.y = ar[4*q+1]; a.z = ar[4*q+2]; a.w = ar[4*q+3];
    b.x = ao[4*q+0] + b_rel[4*q+0];
    b.y = ao[4*q+1] + b_rel[4*q+1];
    b.z = ao[4*q+2] + b_rel[4*q+2];
    b.w = ao[4*q+3] + b_rel[4*q+3];
    pr4[q] = a; ag4[q] = b;
  }
}

// K2: scatter-add 16-wide.  16 threads per edge (f = lane within group).
__global__ __launch_bounds__(256) void k2_scatter16(
    const int* __restrict__ ei, const float* __restrict__ p,
    float* __restrict__ agg, int nE) {
  long long tid = (long long)blockIdx.x * 256 + threadIdx.x;
  if (tid >= (long long)nE * HID) return;
  int e = (int)(tid >> 4), f = (int)(tid & 15);
  int s = ei[e], d = ei[nE + e];
  atomicAdd(agg + (size_t)d * HID + f, p[(size_t)s * HID + f]);
}

// K3: ELU + dual 16x7 projection.  out2 (=d_out) initialized with root part + bias.
__global__ __launch_bounds__(256) void k3_l2(
    const float* __restrict__ agg,
    const float* __restrict__ w_root2, const float* __restrict__ w_rel2,
    const float* __restrict__ b2,
    float* __restrict__ p2, float* __restrict__ out2, int n) {
  int i = blockIdx.x * 256 + threadIdx.x;
  if (i >= n) return;
  const float4* a4 = (const float4*)(agg + (size_t)i * HID);
  float h[HID];
#pragma unroll
  for (int q = 0; q < 4; ++q) {
    float4 v = a4[q];
    float t[4] = {v.x, v.y, v.z, v.w};
#pragma unroll
    for (int j = 0; j < 4; ++j)
      h[4*q + j] = t[j] > 0.f ? t[j] : expm1f(t[j]);
  }
#pragma unroll
  for (int c = 0; c < NCLS; ++c) {
    float sr = 0.f, so = b2[c];
#pragma unroll
    for (int k = 0; k < HID; ++k) {
      sr = fmaf(h[k], w_rel2[k * NCLS + c], sr);
      so = fmaf(h[k], w_root2[k * NCLS + c], so);
    }
    p2[(size_t)i * NCLS + c] = sr;
    out2[(size_t)i * NCLS + c] = so;
  }
}

// K4: scatter-add 7-wide.  8 threads per edge, lane 7 idle.
__global__ __launch_bounds__(256) void k4_scatter7(
    const int* __restrict__ ei, const float* __restrict__ p,
    float* __restrict__ out2, int nE) {
  long long tid = (long long)blockIdx.x * 256 + threadIdx.x;
  int e = (int)(tid >> 3), f = (int)(tid & 7);
  if (e >= nE || f >= NCLS) return;
  int s = ei[e], d = ei[nE + e];
  atomicAdd(out2 + (size_t)d * NCLS + f, p[(size_t)s * NCLS + f]);
}

// K5: in-place log_softmax over 7 classes.
__global__ __launch_bounds__(256) void k5_lsm(float* __restrict__ out, int n) {
  int i = blockIdx.x * 256 + threadIdx.x;
  if (i >= n) return;
  float v[NCLS];
  float* o = out + (size_t)i * NCLS;
#pragma unroll
  for (int c = 0; c < NCLS; ++c) v[c] = o[c];
  float m = v[0];
#pragma unroll
  for (int c = 1; c < NCLS; ++c) m = fmaxf(m, v[c]);
  float s = 0.f;
#pragma unroll
  for (int c = 0; c < NCLS; ++c) s += expf(v[c] - m);
  float l = logf(s);
#pragma unroll
  for (int c = 0; c < NCLS; ++c) o[c] = v[c] - m - l;
}

extern "C" void kernel_launch(void* const* d_in, const int* in_sizes, int n_in,
                              void* d_out, int out_size, void* d_ws, size_t ws_size,
                              hipStream_t stream) {
  const float* x       = (const float*)d_in[0];
  const int*   ei      = (const int*)  d_in[1];
  const float* w_root1 = (const float*)d_in[2];
  const float* w_rel1  = (const float*)d_in[3];
  const float* b_rel1  = (const float*)d_in[4];
  const float* w_root2 = (const float*)d_in[5];
  const float* w_rel2  = (const float*)d_in[6];
  const float* b_rel2  = (const float*)d_in[7];
  float* out = (float*)d_out;

  int n  = in_sizes[0] / FIN;   // 100000
  int nE = in_sizes[1] / 2;     // 3200000

  char* ws   = (char*)d_ws;
  float* p1   = (float*)ws;                                // n*16 f32
  float* agg1 = (float*)(ws + (size_t)n * HID * 4);        // n*16 f32
  float* p2   = (float*)(ws + (size_t)n * HID * 8);        // n*7  f32

  int nb = (n + 255) / 256;
  k1_proj<<<nb, 256, 0, stream>>>(x, w_root1, w_rel1, b_rel1, p1, agg1, n);

  long long t2 = (long long)nE * HID;
  k2_scatter16<<<(int)((t2 + 255) / 256), 256, 0, stream>>>(ei, p1, agg1, nE);

  k3_l2<<<nb, 256, 0, stream>>>(agg1, w_root2, w_rel2, b_rel2, p2, out, n);

  long long t4 = (long long)nE * 8;
  k4_scatter7<<<(int)((t4 + 255) / 256), 256, 0, stream>>>(ei, p2, out, nE);

  k5_lsm<<<nb, 256, 0, stream>>>(out, n);
}